// Round 7
// baseline (254.111 us; speedup 1.0000x reference)
//
#include <hip/hip_runtime.h>
#include <hip/hip_bf16.h>

// AttentionBlock: GroupNorm(8) -> QKV 1x1 -> softmax attention (hw=1024, c=256) -> proj + residual
// B=32, C=256, H=W=32. Inputs fp32, OUTPUT fp32. Internals bf16 MFMA, fp32 accum.
// R7: attn latency-exposure fixes: (1) LDS 85->79.4KB + launch_bounds(256,2) -> 2 blocks/CU
// (2 waves/SIMD TLP); (2) per-block t-tile rotation de-lockstesps the 8 s-split blocks sharing
// an XCD's L2 (one-pass softmax is order-independent); (3) QK chain split into 2 independent
// MFMA accumulators. Grid stays (batch, s-split) for L2 locality (R6: FETCH 141->24.7MB).
// ws: xnT 16MB | qtr 16MB | ktr 16MB | v 16MB | aoT 16MB = 80MB.

typedef __bf16 bf16x8 __attribute__((ext_vector_type(8)));
typedef __bf16 bf16x4 __attribute__((ext_vector_type(4)));
typedef float f32x4 __attribute__((ext_vector_type(4)));
typedef float f32x16 __attribute__((ext_vector_type(16)));

#define MFMA16(a, b, c) __builtin_amdgcn_mfma_f32_16x16x32_bf16(a, b, c, 0, 0, 0)
#define MFMA32(a, b, c) __builtin_amdgcn_mfma_f32_32x32x16_bf16(a, b, c, 0, 0, 0)

// ---------------- K1: GroupNorm, fp32 [b][c][s] -> bf16 xnT [b][s][c] ----------------
__global__ __launch_bounds__(256) void gn_kernel(const float* __restrict__ x,
                                                 const float* __restrict__ gw,
                                                 const float* __restrict__ gb,
                                                 __bf16* __restrict__ xnT) {
    __shared__ float red[8];
    __shared__ float stats[2];
    __shared__ __bf16 Lds[512][40];
    const int b = blockIdx.x >> 3, g = blockIdx.x & 7;
    const size_t base = ((size_t)b * 256 + g * 32) * 1024;
    const float* xp = x + base;
    const int t = threadIdx.x;

    float s = 0.f, s2 = 0.f;
    #pragma unroll
    for (int i = 0; i < 16; i++) {
        int j = i * 256 + t;
        float4 v0 = *(const float4*)(xp + (size_t)j * 8);
        float4 v1 = *(const float4*)(xp + (size_t)j * 8 + 4);
        s  += v0.x + v0.y + v0.z + v0.w + v1.x + v1.y + v1.z + v1.w;
        s2 += v0.x*v0.x + v0.y*v0.y + v0.z*v0.z + v0.w*v0.w
            + v1.x*v1.x + v1.y*v1.y + v1.z*v1.z + v1.w*v1.w;
    }
    #pragma unroll
    for (int o = 32; o > 0; o >>= 1) { s += __shfl_down(s, o, 64); s2 += __shfl_down(s2, o, 64); }
    const int wv = t >> 6;
    if ((t & 63) == 0) { red[wv * 2] = s; red[wv * 2 + 1] = s2; }
    __syncthreads();
    if (t == 0) {
        float ts = 0.f, ts2 = 0.f;
        for (int w = 0; w < 4; w++) { ts += red[w * 2]; ts2 += red[w * 2 + 1]; }
        float mean = ts / 32768.f;
        float var = ts2 / 32768.f - mean * mean;
        stats[0] = mean; stats[1] = rsqrtf(var + 1e-5f);
    }
    __syncthreads();
    const float mean = stats[0], inv = stats[1];

    const int c = t >> 3;
    const int so = (t & 7) * 4;
    const float ga = gw[g * 32 + c], be = gb[g * 32 + c];

    for (int chunk = 0; chunk < 1024; chunk += 512) {
        #pragma unroll
        for (int i = 0; i < 16; i++) {
            int sl = so + i * 32;
            float4 v = *(const float4*)(xp + (size_t)c * 1024 + chunk + sl);
            Lds[sl + 0][c] = (__bf16)((v.x - mean) * inv * ga + be);
            Lds[sl + 1][c] = (__bf16)((v.y - mean) * inv * ga + be);
            Lds[sl + 2][c] = (__bf16)((v.z - mean) * inv * ga + be);
            Lds[sl + 3][c] = (__bf16)((v.w - mean) * inv * ga + be);
        }
        __syncthreads();
        #pragma unroll
        for (int rr = 0; rr < 2; rr++) {
            int sl = rr * 256 + t;
            #pragma unroll
            for (int u = 0; u < 4; u++) {
                bf16x8 vv = *(const bf16x8*)&Lds[sl][u * 8];
                *(bf16x8*)&xnT[((size_t)b * 1024 + chunk + sl) * 256 + g * 32 + u * 8] = vv;
            }
        }
        __syncthreads();
    }
}

// ---------------- shared 128x128 GEMM tile body ----------------
#define GEMM_TILE_BODY(W_, BmatRowBase_)                                            \
    f32x4 acc[4][4] = {};                                                           \
    for (int kk = 0; kk < 256; kk += 32) {                                          \
        {                                                                           \
            int r = t >> 1, kc = (t & 1) * 16;                                      \
            const float* wp = &W_[(size_t)(m0 + r) * 256 + kk + kc];                \
            float4 a0 = *(const float4*)wp;                                         \
            float4 a1 = *(const float4*)(wp + 4);                                   \
            float4 a2 = *(const float4*)(wp + 8);                                   \
            float4 a3 = *(const float4*)(wp + 12);                                  \
            bf16x8 av0, av1;                                                        \
            av0[0] = (__bf16)a0.x; av0[1] = (__bf16)a0.y; av0[2] = (__bf16)a0.z;    \
            av0[3] = (__bf16)a0.w; av0[4] = (__bf16)a1.x; av0[5] = (__bf16)a1.y;    \
            av0[6] = (__bf16)a1.z; av0[7] = (__bf16)a1.w;                           \
            av1[0] = (__bf16)a2.x; av1[1] = (__bf16)a2.y; av1[2] = (__bf16)a2.z;    \
            av1[3] = (__bf16)a2.w; av1[4] = (__bf16)a3.x; av1[5] = (__bf16)a3.y;    \
            av1[6] = (__bf16)a3.z; av1[7] = (__bf16)a3.w;                           \
            *(bf16x8*)&As[r][kc] = av0;                                             \
            *(bf16x8*)&As[r][kc + 8] = av1;                                         \
            const __bf16* bp = &(BmatRowBase_)[(size_t)(n0 + r) * 256 + kk + kc];   \
            *(bf16x8*)&Bs[r][kc] = *(const bf16x8*)bp;                              \
            *(bf16x8*)&Bs[r][kc + 8] = *(const bf16x8*)(bp + 8);                    \
        }                                                                           \
        __syncthreads();                                                            \
        bf16x8 af[4], bfv[4];                                                       \
        _Pragma("unroll")                                                           \
        for (int im = 0; im < 4; im++)                                              \
            af[im] = *(const bf16x8*)&As[wm + im * 16 + l16][quad * 8];             \
        _Pragma("unroll")                                                           \
        for (int in = 0; in < 4; in++)                                              \
            bfv[in] = *(const bf16x8*)&Bs[wn + in * 16 + l16][quad * 8];            \
        _Pragma("unroll")                                                           \
        for (int im = 0; im < 4; im++)                                              \
            _Pragma("unroll")                                                       \
            for (int in = 0; in < 4; in++)                                          \
                acc[im][in] = MFMA16(af[im], bfv[in], acc[im][in]);                 \
        __syncthreads();                                                            \
    }

// ---------------- K2: QKV GEMM, 128x128 tiles ----------------
__global__ __launch_bounds__(256) void qkv_gemm(const float* __restrict__ W,
                                                const float* __restrict__ bias,
                                                const __bf16* __restrict__ xnT,
                                                __bf16* __restrict__ qtr,
                                                __bf16* __restrict__ ktr,
                                                __bf16* __restrict__ vbuf) {
    __shared__ __bf16 As[128][40];
    __shared__ __bf16 Bs[128][40];
    const int b = blockIdx.z;
    const int n0 = blockIdx.x * 128, m0 = blockIdx.y * 128;
    const int t = threadIdx.x;
    const int wave = t >> 6, lane = t & 63, quad = lane >> 4, l16 = lane & 15;
    const int wm = (wave & 1) * 64, wn = (wave >> 1) * 64;
    const __bf16* brow = xnT + (size_t)b * 1024 * 256;

    GEMM_TILE_BODY(W, brow)

    #pragma unroll
    for (int im = 0; im < 4; im++) {
        #pragma unroll
        for (int in = 0; in < 4; in++) {
            int sg = n0 + wn + in * 16 + l16;
            int ob = m0 + wm + im * 16 + quad * 4;
            if (m0 < 512) {
                bf16x4 ov;
                #pragma unroll
                for (int r = 0; r < 4; r++) ov[r] = (__bf16)(acc[im][in][r] + bias[ob + r]);
                __bf16* dst = (m0 < 256) ? &qtr[((size_t)b * 1024 + sg) * 256 + ob]
                                         : &ktr[((size_t)b * 1024 + sg) * 256 + (ob - 256)];
                *(bf16x4*)dst = ov;
            } else {
                #pragma unroll
                for (int r = 0; r < 4; r++) {
                    float val = acc[im][in][r] + bias[ob + r];
                    vbuf[((size_t)b * 256 + (ob - 512 + r)) * 1024 + sg] = (__bf16)val;
                }
            }
        }
    }
}

// ---------------- K3: fused flash attention, 32x32x16 MFMA, one-pass softmax ----------------
// grid (32 b, 8 s-split). 79.4KB LDS -> 2 blocks/CU. Per-block t-tile rotation breaks the
// lockstep same-address L2 hammering among the 8 s-split blocks of a batch.
__global__ __launch_bounds__(256, 2) void attn_kernel(const __bf16* __restrict__ qtr,
                                                      const __bf16* __restrict__ ktr,
                                                      const __bf16* __restrict__ vbuf,
                                                      __bf16* __restrict__ aoT) {
    __shared__ __bf16 KtS[2][32][260];  // [buf][t_local][c]
    __shared__ __bf16 Vs[2][256][36];   // [buf][c][t_local]
    __shared__ __bf16 Pl[4][32][36];    // per-wave P [s_local][t_local]
    const int b = blockIdx.x;
    const int tid = threadIdx.x;
    const int wave = tid >> 6, lane = tid & 63, half = lane >> 5, l31 = lane & 31;
    const int s0 = blockIdx.y * 128 + wave * 32;
    const int rot = blockIdx.y * 4;     // t-tile rotation (order-independent softmax)
    const float kscale = 0.09016844f;   // (1/16) * log2(e); p = exp2(s * kscale)

    bf16x8 aq[16];
    #pragma unroll
    for (int ks = 0; ks < 16; ks++)
        aq[ks] = *(const bf16x8*)&qtr[((size_t)b * 1024 + s0 + l31) * 256 + ks * 16 + half * 8];

    const int kr_row = tid & 31;
    const int kr_cb  = (tid >> 5) * 32;
    const int vs_c   = tid >> 2;
    const int vs_seg = (tid & 3) * 8;

    bf16x8 kr[4], vr[4];
    {
        const int t0 = (rot & 31) * 32;
        #pragma unroll
        for (int u = 0; u < 4; u++)
            kr[u] = *(const bf16x8*)&ktr[((size_t)b * 1024 + t0 + kr_row) * 256 + kr_cb + u * 8];
        #pragma unroll
        for (int i = 0; i < 4; i++)
            vr[i] = *(const bf16x8*)&vbuf[((size_t)b * 256 + i * 64 + vs_c) * 1024 + t0 + vs_seg];
    }
    #pragma unroll
    for (int u = 0; u < 4; u++) *(bf16x8*)&KtS[0][kr_row][kr_cb + u * 8] = kr[u];
    #pragma unroll
    for (int i = 0; i < 4; i++) *(bf16x8*)&Vs[0][i * 64 + vs_c][vs_seg] = vr[i];
    __syncthreads();

    float l_part[16] = {};
    f32x16 o_acc[8] = {};

    for (int tt = 0; tt < 32; tt++) {
        const int cur = tt & 1;
        if (tt < 31) {
            const int t0 = ((rot + tt + 1) & 31) * 32;
            #pragma unroll
            for (int u = 0; u < 4; u++)
                kr[u] = *(const bf16x8*)&ktr[((size_t)b * 1024 + t0 + kr_row) * 256 + kr_cb + u * 8];
            #pragma unroll
            for (int i = 0; i < 4; i++)
                vr[i] = *(const bf16x8*)&vbuf[((size_t)b * 256 + i * 64 + vs_c) * 1024 + t0 + vs_seg];
        }

        // QK^T: two independent 8-chains for ILP, merged in softmax
        f32x16 sc_a = {}, sc_b = {};
        #pragma unroll
        for (int ks = 0; ks < 8; ks++) {
            bf16x8 bk0 = *(const bf16x8*)&KtS[cur][l31][ks * 16 + half * 8];
            bf16x8 bk1 = *(const bf16x8*)&KtS[cur][l31][(ks + 8) * 16 + half * 8];
            sc_a = MFMA32(aq[ks], bk0, sc_a);
            sc_b = MFMA32(aq[ks + 8], bk1, sc_b);
        }

        #pragma unroll
        for (int r = 0; r < 16; r++) {
            float p = exp2f((sc_a[r] + sc_b[r]) * kscale);
            l_part[r] += p;
            int row = (r & 3) + 8 * (r >> 2) + 4 * half;
            Pl[wave][row][l31] = (__bf16)p;
        }

        bf16x8 ap0 = *(const bf16x8*)&Pl[wave][l31][half * 8];
        bf16x8 ap1 = *(const bf16x8*)&Pl[wave][l31][16 + half * 8];
        #pragma unroll
        for (int n = 0; n < 8; n++) {
            bf16x8 bv0 = *(const bf16x8*)&Vs[cur][n * 32 + l31][half * 8];
            bf16x8 bv1 = *(const bf16x8*)&Vs[cur][n * 32 + l31][16 + half * 8];
            o_acc[n] = MFMA32(ap0, bv0, o_acc[n]);
            o_acc[n] = MFMA32(ap1, bv1, o_acc[n]);
        }

        if (tt < 31) {
            #pragma unroll
            for (int u = 0; u < 4; u++) *(bf16x8*)&KtS[1 - cur][kr_row][kr_cb + u * 8] = kr[u];
            #pragma unroll
            for (int i = 0; i < 4; i++) *(bf16x8*)&Vs[1 - cur][i * 64 + vs_c][vs_seg] = vr[i];
        }
        __syncthreads();
    }

    #pragma unroll
    for (int r = 0; r < 16; r++) {
        float l = l_part[r];
        #pragma unroll
        for (int m = 16; m > 0; m >>= 1) l += __shfl_xor(l, m, 32);
        float rinv = 1.0f / l;
        int row = (r & 3) + 8 * (r >> 2) + 4 * half;
        #pragma unroll
        for (int n = 0; n < 8; n++)
            aoT[((size_t)b * 1024 + s0 + row) * 256 + n * 32 + l31] = (__bf16)(o_acc[n][r] * rinv);
    }
}

// ---------------- K4: proj GEMM, 128x128 tiles ----------------
__global__ __launch_bounds__(256) void proj_gemm(const float* __restrict__ W,
                                                 const float* __restrict__ bias,
                                                 const __bf16* __restrict__ aoT,
                                                 const float* __restrict__ resid,
                                                 float* __restrict__ Out) {
    __shared__ __bf16 As[128][40];
    __shared__ __bf16 Bs[128][40];
    const int b = blockIdx.z;
    const int n0 = blockIdx.x * 128, m0 = blockIdx.y * 128;
    const int t = threadIdx.x;
    const int wave = t >> 6, lane = t & 63, quad = lane >> 4, l16 = lane & 15;
    const int wm = (wave & 1) * 64, wn = (wave >> 1) * 64;
    const __bf16* brow = aoT + (size_t)b * 1024 * 256;

    GEMM_TILE_BODY(W, brow)

    #pragma unroll
    for (int im = 0; im < 4; im++) {
        #pragma unroll
        for (int in = 0; in < 4; in++) {
            int sg = n0 + wn + in * 16 + l16;
            int ob = m0 + wm + im * 16 + quad * 4;
            #pragma unroll
            for (int r = 0; r < 4; r++) {
                int o = ob + r;
                size_t idx = ((size_t)b * 256 + o) * 1024 + sg;
                Out[idx] = acc[im][in][r] + bias[o] + resid[idx];
            }
        }
    }
}

extern "C" void kernel_launch(void* const* d_in, const int* in_sizes, int n_in,
                              void* d_out, int out_size, void* d_ws, size_t ws_size,
                              hipStream_t stream) {
    const float* x    = (const float*)d_in[0];
    const float* gw   = (const float*)d_in[1];
    const float* gb   = (const float*)d_in[2];
    const float* wqkv = (const float*)d_in[3];
    const float* bqkv = (const float*)d_in[4];
    const float* wout = (const float*)d_in[5];
    const float* bout = (const float*)d_in[6];
    float* out = (float*)d_out;

    const size_t T16 = (size_t)32 * 1024 * 256;
    __bf16* xnT  = (__bf16*)d_ws;        // [b][s][c]
    __bf16* qtr  = xnT + T16;            // [b][s][c]
    __bf16* ktr  = qtr + T16;            // [b][t][c]
    __bf16* vbuf = ktr + T16;            // [b][c][t]
    __bf16* aoT  = vbuf + T16;           // [b][s][c]

    gn_kernel<<<dim3(256), 256, 0, stream>>>(x, gw, gb, xnT);
    qkv_gemm<<<dim3(8, 6, 32), 256, 0, stream>>>(wqkv, bqkv, xnT, qtr, ktr, vbuf);
    attn_kernel<<<dim3(32, 8), 256, 0, stream>>>(qtr, ktr, vbuf, aoT);
    proj_gemm<<<dim3(8, 2, 32), 256, 0, stream>>>(wout, bout, aoT, x, out);
}

// Round 8
// 219.667 us; speedup vs baseline: 1.1568x; 1.1568x over previous
//
#include <hip/hip_runtime.h>
#include <hip/hip_bf16.h>

// AttentionBlock: GroupNorm(8) -> QKV 1x1 -> softmax attention (hw=1024, c=256) -> proj + residual
// B=32, C=256, H=W=32. Inputs fp32, OUTPUT fp32. Internals bf16 MFMA, fp32 accum.
// R8: attn rebuilt as 512-thread blocks (8 waves = 2 waves/SIMD TLP; R7 showed 256-block grid
// caps at 1 block/CU so occupancy must come from block size). Waves split t (QK) and c (PV):
// wave w: rows (w&3)*32, t-half w>>2. P crosses the pair via LDS Pl[pair][s][64t]. Each wave's
// O covers a disjoint 128-c half (o_acc 64 VGPRs) -> only scalar l merged at end.
// Grid back to b-major (32,8), NO rotation (R7's rotation broke L2 tile reuse: FETCH 25->52MB).
// ws: xnT 16MB | qtr 16MB | ktr 16MB | v 16MB | aoT 16MB = 80MB.

typedef __bf16 bf16x8 __attribute__((ext_vector_type(8)));
typedef __bf16 bf16x4 __attribute__((ext_vector_type(4)));
typedef float f32x4 __attribute__((ext_vector_type(4)));
typedef float f32x16 __attribute__((ext_vector_type(16)));

#define MFMA16(a, b, c) __builtin_amdgcn_mfma_f32_16x16x32_bf16(a, b, c, 0, 0, 0)
#define MFMA32(a, b, c) __builtin_amdgcn_mfma_f32_32x32x16_bf16(a, b, c, 0, 0, 0)

// ---------------- K1: GroupNorm, fp32 [b][c][s] -> bf16 xnT [b][s][c] ----------------
__global__ __launch_bounds__(256) void gn_kernel(const float* __restrict__ x,
                                                 const float* __restrict__ gw,
                                                 const float* __restrict__ gb,
                                                 __bf16* __restrict__ xnT) {
    __shared__ float red[8];
    __shared__ float stats[2];
    __shared__ __bf16 Lds[512][40];
    const int b = blockIdx.x >> 3, g = blockIdx.x & 7;
    const size_t base = ((size_t)b * 256 + g * 32) * 1024;
    const float* xp = x + base;
    const int t = threadIdx.x;

    float s = 0.f, s2 = 0.f;
    #pragma unroll
    for (int i = 0; i < 16; i++) {
        int j = i * 256 + t;
        float4 v0 = *(const float4*)(xp + (size_t)j * 8);
        float4 v1 = *(const float4*)(xp + (size_t)j * 8 + 4);
        s  += v0.x + v0.y + v0.z + v0.w + v1.x + v1.y + v1.z + v1.w;
        s2 += v0.x*v0.x + v0.y*v0.y + v0.z*v0.z + v0.w*v0.w
            + v1.x*v1.x + v1.y*v1.y + v1.z*v1.z + v1.w*v1.w;
    }
    #pragma unroll
    for (int o = 32; o > 0; o >>= 1) { s += __shfl_down(s, o, 64); s2 += __shfl_down(s2, o, 64); }
    const int wv = t >> 6;
    if ((t & 63) == 0) { red[wv * 2] = s; red[wv * 2 + 1] = s2; }
    __syncthreads();
    if (t == 0) {
        float ts = 0.f, ts2 = 0.f;
        for (int w = 0; w < 4; w++) { ts += red[w * 2]; ts2 += red[w * 2 + 1]; }
        float mean = ts / 32768.f;
        float var = ts2 / 32768.f - mean * mean;
        stats[0] = mean; stats[1] = rsqrtf(var + 1e-5f);
    }
    __syncthreads();
    const float mean = stats[0], inv = stats[1];

    const int c = t >> 3;
    const int so = (t & 7) * 4;
    const float ga = gw[g * 32 + c], be = gb[g * 32 + c];

    for (int chunk = 0; chunk < 1024; chunk += 512) {
        #pragma unroll
        for (int i = 0; i < 16; i++) {
            int sl = so + i * 32;
            float4 v = *(const float4*)(xp + (size_t)c * 1024 + chunk + sl);
            Lds[sl + 0][c] = (__bf16)((v.x - mean) * inv * ga + be);
            Lds[sl + 1][c] = (__bf16)((v.y - mean) * inv * ga + be);
            Lds[sl + 2][c] = (__bf16)((v.z - mean) * inv * ga + be);
            Lds[sl + 3][c] = (__bf16)((v.w - mean) * inv * ga + be);
        }
        __syncthreads();
        #pragma unroll
        for (int rr = 0; rr < 2; rr++) {
            int sl = rr * 256 + t;
            #pragma unroll
            for (int u = 0; u < 4; u++) {
                bf16x8 vv = *(const bf16x8*)&Lds[sl][u * 8];
                *(bf16x8*)&xnT[((size_t)b * 1024 + chunk + sl) * 256 + g * 32 + u * 8] = vv;
            }
        }
        __syncthreads();
    }
}

// ---------------- shared 128x128 GEMM tile body ----------------
#define GEMM_TILE_BODY(W_, BmatRowBase_)                                            \
    f32x4 acc[4][4] = {};                                                           \
    for (int kk = 0; kk < 256; kk += 32) {                                          \
        {                                                                           \
            int r = t >> 1, kc = (t & 1) * 16;                                      \
            const float* wp = &W_[(size_t)(m0 + r) * 256 + kk + kc];                \
            float4 a0 = *(const float4*)wp;                                         \
            float4 a1 = *(const float4*)(wp + 4);                                   \
            float4 a2 = *(const float4*)(wp + 8);                                   \
            float4 a3 = *(const float4*)(wp + 12);                                  \
            bf16x8 av0, av1;                                                        \
            av0[0] = (__bf16)a0.x; av0[1] = (__bf16)a0.y; av0[2] = (__bf16)a0.z;    \
            av0[3] = (__bf16)a0.w; av0[4] = (__bf16)a1.x; av0[5] = (__bf16)a1.y;    \
            av0[6] = (__bf16)a1.z; av0[7] = (__bf16)a1.w;                           \
            av1[0] = (__bf16)a2.x; av1[1] = (__bf16)a2.y; av1[2] = (__bf16)a2.z;    \
            av1[3] = (__bf16)a2.w; av1[4] = (__bf16)a3.x; av1[5] = (__bf16)a3.y;    \
            av1[6] = (__bf16)a3.z; av1[7] = (__bf16)a3.w;                           \
            *(bf16x8*)&As[r][kc] = av0;                                             \
            *(bf16x8*)&As[r][kc + 8] = av1;                                         \
            const __bf16* bp = &(BmatRowBase_)[(size_t)(n0 + r) * 256 + kk + kc];   \
            *(bf16x8*)&Bs[r][kc] = *(const bf16x8*)bp;                              \
            *(bf16x8*)&Bs[r][kc + 8] = *(const bf16x8*)(bp + 8);                    \
        }                                                                           \
        __syncthreads();                                                            \
        bf16x8 af[4], bfv[4];                                                       \
        _Pragma("unroll")                                                           \
        for (int im = 0; im < 4; im++)                                              \
            af[im] = *(const bf16x8*)&As[wm + im * 16 + l16][quad * 8];             \
        _Pragma("unroll")                                                           \
        for (int in = 0; in < 4; in++)                                              \
            bfv[in] = *(const bf16x8*)&Bs[wn + in * 16 + l16][quad * 8];            \
        _Pragma("unroll")                                                           \
        for (int im = 0; im < 4; im++)                                              \
            _Pragma("unroll")                                                       \
            for (int in = 0; in < 4; in++)                                          \
                acc[im][in] = MFMA16(af[im], bfv[in], acc[im][in]);                 \
        __syncthreads();                                                            \
    }

// ---------------- K2: QKV GEMM, 128x128 tiles ----------------
__global__ __launch_bounds__(256) void qkv_gemm(const float* __restrict__ W,
                                                const float* __restrict__ bias,
                                                const __bf16* __restrict__ xnT,
                                                __bf16* __restrict__ qtr,
                                                __bf16* __restrict__ ktr,
                                                __bf16* __restrict__ vbuf) {
    __shared__ __bf16 As[128][40];
    __shared__ __bf16 Bs[128][40];
    const int b = blockIdx.z;
    const int n0 = blockIdx.x * 128, m0 = blockIdx.y * 128;
    const int t = threadIdx.x;
    const int wave = t >> 6, lane = t & 63, quad = lane >> 4, l16 = lane & 15;
    const int wm = (wave & 1) * 64, wn = (wave >> 1) * 64;
    const __bf16* brow = xnT + (size_t)b * 1024 * 256;

    GEMM_TILE_BODY(W, brow)

    #pragma unroll
    for (int im = 0; im < 4; im++) {
        #pragma unroll
        for (int in = 0; in < 4; in++) {
            int sg = n0 + wn + in * 16 + l16;
            int ob = m0 + wm + im * 16 + quad * 4;
            if (m0 < 512) {
                bf16x4 ov;
                #pragma unroll
                for (int r = 0; r < 4; r++) ov[r] = (__bf16)(acc[im][in][r] + bias[ob + r]);
                __bf16* dst = (m0 < 256) ? &qtr[((size_t)b * 1024 + sg) * 256 + ob]
                                         : &ktr[((size_t)b * 1024 + sg) * 256 + (ob - 256)];
                *(bf16x4*)dst = ov;
            } else {
                #pragma unroll
                for (int r = 0; r < 4; r++) {
                    float val = acc[im][in][r] + bias[ob + r];
                    vbuf[((size_t)b * 256 + (ob - 512 + r)) * 1024 + sg] = (__bf16)val;
                }
            }
        }
    }
}

// ---------------- K3: fused flash attention, 512 threads, t-split QK / c-split PV ----------------
// grid (32 b, 8 s-split), 8 waves. Wave w: rows (w&3)*32 within the 128-row block, t-half th=w>>2.
// Per iter (64 t): stage K/V pair -> B -> QK own t-half, P -> Pl -> B -> PV all 64 t, own c-half -> B.
__global__ __launch_bounds__(512, 2) void attn_kernel(const __bf16* __restrict__ qtr,
                                                      const __bf16* __restrict__ ktr,
                                                      const __bf16* __restrict__ vbuf,
                                                      __bf16* __restrict__ aoT) {
    __shared__ __bf16 Kt[2][32][260];   // [t-half][t_local][c]
    __shared__ __bf16 Vs[2][256][36];   // [t-half][c][t_local]
    __shared__ __bf16 Pl[4][32][72];    // [pair][s_local][t64]
    __shared__ float Lred[4][2][32];    // [pair][th][row]
    const int b = blockIdx.x;
    const int tid = threadIdx.x;
    const int wave = tid >> 6, lane = tid & 63, half = lane >> 5, l31 = lane & 31;
    const int pair = wave & 3, th = wave >> 2;
    const int s0 = blockIdx.y * 128 + pair * 32;
    const float kscale = 0.09016844f;   // (1/16) * log2(e); p = exp2(s * kscale)

    // Q A-fragments (also valid as B-operand layout): aq[ks][j] = Q[s0+l31][ks*16 + half*8 + j]
    bf16x8 aq[16];
    #pragma unroll
    for (int ks = 0; ks < 16; ks++)
        aq[ks] = *(const bf16x8*)&qtr[((size_t)b * 1024 + s0 + l31) * 256 + ks * 16 + half * 8];

    // staging coords
    const int k_row = tid >> 3;           // 0..63: t within pair
    const int k_cb  = (tid & 7) * 8;      // c base; u steps +64 (8 lanes cover 128B contiguous)
    const int v_c   = tid >> 1;           // 0..255
    const int v_th  = tid & 1;            // t-half
    const size_t kbase = (size_t)b * 1024 * 256;
    const size_t vbase = (size_t)b * 256 * 1024;

    float l_part[16] = {};
    f32x16 o_acc[4] = {};                 // O[32 s][128 c-half]: 4 chunks of 32 c

    for (int it = 0; it < 16; it++) {
        const int t0 = it * 64;
        // ---- stage K/V pair (64 t) ----
        #pragma unroll
        for (int u = 0; u < 4; u++) {
            bf16x8 kv = *(const bf16x8*)&ktr[kbase + (size_t)(t0 + k_row) * 256 + k_cb + u * 64];
            *(bf16x8*)&Kt[k_row >> 5][k_row & 31][k_cb + u * 64] = kv;
        }
        #pragma unroll
        for (int u = 0; u < 4; u++) {
            bf16x8 vv = *(const bf16x8*)&vbuf[vbase + (size_t)v_c * 1024 + t0 + v_th * 32 + u * 8];
            *(bf16x8*)&Vs[v_th][v_c][u * 8] = vv;
        }
        __syncthreads();

        // ---- QK^T on own t-half: S[32 s][32 t], two 8-chains ----
        f32x16 sc_a = {}, sc_b = {};
        #pragma unroll
        for (int ks = 0; ks < 8; ks++) {
            bf16x8 bk0 = *(const bf16x8*)&Kt[th][l31][ks * 16 + half * 8];
            bf16x8 bk1 = *(const bf16x8*)&Kt[th][l31][(ks + 8) * 16 + half * 8];
            sc_a = MFMA32(aq[ks], bk0, sc_a);
            sc_b = MFMA32(aq[ks + 8], bk1, sc_b);
        }
        #pragma unroll
        for (int r = 0; r < 16; r++) {
            float p = exp2f((sc_a[r] + sc_b[r]) * kscale);
            l_part[r] += p;
            int row = (r & 3) + 8 * (r >> 2) + 4 * half;
            Pl[pair][row][th * 32 + l31] = (__bf16)p;
        }
        __syncthreads();

        // ---- PV over all 64 t, own 128-c half ----
        bf16x8 ap[4];
        #pragma unroll
        for (int kc = 0; kc < 4; kc++)
            ap[kc] = *(const bf16x8*)&Pl[pair][l31][kc * 16 + half * 8];
        #pragma unroll
        for (int n = 0; n < 4; n++) {
            int c = th * 128 + n * 32 + l31;
            #pragma unroll
            for (int kc = 0; kc < 4; kc++) {
                bf16x8 bv = *(const bf16x8*)&Vs[kc >> 1][c][(kc & 1) * 16 + half * 8];
                o_acc[n] = MFMA32(ap[kc], bv, o_acc[n]);
            }
        }
        __syncthreads();
    }

    // ---- merge denominators across the pair, normalize, write own c-half ----
    float lsum[16];
    #pragma unroll
    for (int r = 0; r < 16; r++) {
        float l = l_part[r];
        #pragma unroll
        for (int m = 16; m > 0; m >>= 1) l += __shfl_xor(l, m, 32);
        lsum[r] = l;
        if (l31 == 0) {
            int row = (r & 3) + 8 * (r >> 2) + 4 * half;
            Lred[pair][th][row] = l;
        }
    }
    __syncthreads();
    #pragma unroll
    for (int r = 0; r < 16; r++) {
        int row = (r & 3) + 8 * (r >> 2) + 4 * half;
        float rinv = 1.0f / (lsum[r] + Lred[pair][1 - th][row]);
        #pragma unroll
        for (int n = 0; n < 4; n++) {
            int c = th * 128 + n * 32 + l31;
            aoT[((size_t)b * 1024 + s0 + row) * 256 + c] = (__bf16)(o_acc[n][r] * rinv);
        }
    }
}

// ---------------- K4: proj GEMM, 128x128 tiles ----------------
__global__ __launch_bounds__(256) void proj_gemm(const float* __restrict__ W,
                                                 const float* __restrict__ bias,
                                                 const __bf16* __restrict__ aoT,
                                                 const float* __restrict__ resid,
                                                 float* __restrict__ Out) {
    __shared__ __bf16 As[128][40];
    __shared__ __bf16 Bs[128][40];
    const int b = blockIdx.z;
    const int n0 = blockIdx.x * 128, m0 = blockIdx.y * 128;
    const int t = threadIdx.x;
    const int wave = t >> 6, lane = t & 63, quad = lane >> 4, l16 = lane & 15;
    const int wm = (wave & 1) * 64, wn = (wave >> 1) * 64;
    const __bf16* brow = aoT + (size_t)b * 1024 * 256;

    GEMM_TILE_BODY(W, brow)

    #pragma unroll
    for (int im = 0; im < 4; im++) {
        #pragma unroll
        for (int in = 0; in < 4; in++) {
            int sg = n0 + wn + in * 16 + l16;
            int ob = m0 + wm + im * 16 + quad * 4;
            #pragma unroll
            for (int r = 0; r < 4; r++) {
                int o = ob + r;
                size_t idx = ((size_t)b * 256 + o) * 1024 + sg;
                Out[idx] = acc[im][in][r] + bias[o] + resid[idx];
            }
        }
    }
}

extern "C" void kernel_launch(void* const* d_in, const int* in_sizes, int n_in,
                              void* d_out, int out_size, void* d_ws, size_t ws_size,
                              hipStream_t stream) {
    const float* x    = (const float*)d_in[0];
    const float* gw   = (const float*)d_in[1];
    const float* gb   = (const float*)d_in[2];
    const float* wqkv = (const float*)d_in[3];
    const float* bqkv = (const float*)d_in[4];
    const float* wout = (const float*)d_in[5];
    const float* bout = (const float*)d_in[6];
    float* out = (float*)d_out;

    const size_t T16 = (size_t)32 * 1024 * 256;
    __bf16* xnT  = (__bf16*)d_ws;        // [b][s][c]
    __bf16* qtr  = xnT + T16;            // [b][s][c]
    __bf16* ktr  = qtr + T16;            // [b][t][c]
    __bf16* vbuf = ktr + T16;            // [b][c][t]
    __bf16* aoT  = vbuf + T16;           // [b][s][c]

    gn_kernel<<<dim3(256), 256, 0, stream>>>(x, gw, gb, xnT);
    qkv_gemm<<<dim3(8, 6, 32), 256, 0, stream>>>(wqkv, bqkv, xnT, qtr, ktr, vbuf);
    attn_kernel<<<dim3(32, 8), 512, 0, stream>>>(qtr, ktr, vbuf, aoT);
    proj_gemm<<<dim3(8, 2, 32), 256, 0, stream>>>(wout, bout, aoT, x, out);
}

// Round 9
// 211.352 us; speedup vs baseline: 1.2023x; 1.0393x over previous
//
#include <hip/hip_runtime.h>
#include <hip/hip_bf16.h>

// AttentionBlock: GroupNorm(8) -> QKV 1x1 -> softmax attention (hw=1024, c=256) -> proj + residual
// B=32, C=256, H=W=32. Inputs fp32, OUTPUT fp32. Internals bf16 MFMA, fp32 accum.
// R9: support kernels attacked (R8 showed attn=66us of 220 -> gn+qkv+proj ~154us):
//  - wconv: one-time fp32->bf16 weight convert (GEMM A staging becomes bf16, half bytes, no cvt)
//  - GEMMs: BK=64 (4 iters, half the barriers) + register prefetch of tile k+1 hidden behind
//    MFMA of tile k. LDS stride 72 (36 dw): staging writes & frag reads all <=2-way (free).
//  - gn: 512 threads (2 waves/SIMD latency hiding).  attn unchanged from R8 (65.7us anchor).
// ws: xnT 16MB | qtr 16MB | ktr 16MB | v 16MB | aoT 16MB | wbf 512KB.

typedef __bf16 bf16x8 __attribute__((ext_vector_type(8)));
typedef __bf16 bf16x4 __attribute__((ext_vector_type(4)));
typedef float f32x4 __attribute__((ext_vector_type(4)));
typedef float f32x16 __attribute__((ext_vector_type(16)));

#define MFMA16(a, b, c) __builtin_amdgcn_mfma_f32_16x16x32_bf16(a, b, c, 0, 0, 0)
#define MFMA32(a, b, c) __builtin_amdgcn_mfma_f32_32x32x16_bf16(a, b, c, 0, 0, 0)

// ---------------- K0: weight fp32 -> bf16 (wqkv 768x256 | wout 256x256 concatenated) ----------------
__global__ __launch_bounds__(256) void wconv_kernel(const float* __restrict__ wqkv,
                                                    const float* __restrict__ wout,
                                                    __bf16* __restrict__ wbf) {
    int idx = (blockIdx.x * 256 + threadIdx.x) * 8;   // 128 blocks * 256 * 8 = 262144
    const float* src = (idx < 196608) ? (wqkv + idx) : (wout + (idx - 196608));
    float4 v0 = *(const float4*)src;
    float4 v1 = *(const float4*)(src + 4);
    bf16x8 o;
    o[0] = (__bf16)v0.x; o[1] = (__bf16)v0.y; o[2] = (__bf16)v0.z; o[3] = (__bf16)v0.w;
    o[4] = (__bf16)v1.x; o[5] = (__bf16)v1.y; o[6] = (__bf16)v1.z; o[7] = (__bf16)v1.w;
    *(bf16x8*)&wbf[idx] = o;
}

// ---------------- K1: GroupNorm, fp32 [b][c][s] -> bf16 xnT [b][s][c], 512 threads ----------------
__global__ __launch_bounds__(512) void gn_kernel(const float* __restrict__ x,
                                                 const float* __restrict__ gw,
                                                 const float* __restrict__ gb,
                                                 __bf16* __restrict__ xnT) {
    __shared__ float red[16];
    __shared__ float stats[2];
    __shared__ __bf16 Lds[512][40];
    const int b = blockIdx.x >> 3, g = blockIdx.x & 7;
    const size_t base = ((size_t)b * 256 + g * 32) * 1024;
    const float* xp = x + base;
    const int t = threadIdx.x;                // 0..511

    float s = 0.f, s2 = 0.f;
    #pragma unroll
    for (int i = 0; i < 8; i++) {
        int j = i * 512 + t;                  // 8-elem chunk index
        float4 v0 = *(const float4*)(xp + (size_t)j * 8);
        float4 v1 = *(const float4*)(xp + (size_t)j * 8 + 4);
        s  += v0.x + v0.y + v0.z + v0.w + v1.x + v1.y + v1.z + v1.w;
        s2 += v0.x*v0.x + v0.y*v0.y + v0.z*v0.z + v0.w*v0.w
            + v1.x*v1.x + v1.y*v1.y + v1.z*v1.z + v1.w*v1.w;
    }
    #pragma unroll
    for (int o = 32; o > 0; o >>= 1) { s += __shfl_down(s, o, 64); s2 += __shfl_down(s2, o, 64); }
    const int wv = t >> 6;
    if ((t & 63) == 0) { red[wv * 2] = s; red[wv * 2 + 1] = s2; }
    __syncthreads();
    if (t == 0) {
        float ts = 0.f, ts2 = 0.f;
        for (int w = 0; w < 8; w++) { ts += red[w * 2]; ts2 += red[w * 2 + 1]; }
        float mean = ts / 32768.f;
        float var = ts2 / 32768.f - mean * mean;
        stats[0] = mean; stats[1] = rsqrtf(var + 1e-5f);
    }
    __syncthreads();
    const float mean = stats[0], inv = stats[1];

    const int c = t >> 4;                 // 0..31 channel within group
    const int so = (t & 15) * 2;          // s sub-offset (pairs)
    const float ga = gw[g * 32 + c], be = gb[g * 32 + c];

    for (int chunk = 0; chunk < 1024; chunk += 512) {
        #pragma unroll
        for (int i = 0; i < 16; i++) {
            int sl = so + i * 32;
            float2 v = *(const float2*)(xp + (size_t)c * 1024 + chunk + sl);
            Lds[sl][c]     = (__bf16)((v.x - mean) * inv * ga + be);
            Lds[sl + 1][c] = (__bf16)((v.y - mean) * inv * ga + be);
        }
        __syncthreads();
        {
            int sl = t;                   // one s-row per thread
            #pragma unroll
            for (int u = 0; u < 4; u++) {
                bf16x8 vv = *(const bf16x8*)&Lds[sl][u * 8];
                *(bf16x8*)&xnT[((size_t)b * 1024 + chunk + sl) * 256 + g * 32 + u * 8] = vv;
            }
        }
        __syncthreads();
    }
}

// ---------------- shared 128x128 GEMM body, BK=64, register-prefetch pipeline ----------------
// A = Wbf (bf16) rows m0.., B = src rows (b*1024+n0).., K=256 in 4 iters of 64.
#define GEMM64_BODY(ArowBase_, BrowBase_)                                               \
    f32x4 acc[4][4] = {};                                                               \
    const int r_ = t >> 1, kc_ = (t & 1) * 32;                                          \
    bf16x8 pa[4], pb[4];                                                                \
    _Pragma("unroll")                                                                   \
    for (int u = 0; u < 4; u++) {                                                       \
        pa[u] = *(const bf16x8*)&(ArowBase_)[(size_t)r_ * 256 + kc_ + u * 8];           \
        pb[u] = *(const bf16x8*)&(BrowBase_)[(size_t)r_ * 256 + kc_ + u * 8];           \
    }                                                                                   \
    for (int kk = 0; kk < 256; kk += 64) {                                              \
        _Pragma("unroll")                                                               \
        for (int u = 0; u < 4; u++) {                                                   \
            *(bf16x8*)&As[r_][kc_ + u * 8] = pa[u];                                     \
            *(bf16x8*)&Bs[r_][kc_ + u * 8] = pb[u];                                     \
        }                                                                               \
        __syncthreads();                                                                \
        if (kk < 192) {                                                                 \
            _Pragma("unroll")                                                           \
            for (int u = 0; u < 4; u++) {                                               \
                pa[u] = *(const bf16x8*)&(ArowBase_)[(size_t)r_ * 256 + kk + 64 + kc_ + u * 8]; \
                pb[u] = *(const bf16x8*)&(BrowBase_)[(size_t)r_ * 256 + kk + 64 + kc_ + u * 8]; \
            }                                                                           \
        }                                                                               \
        _Pragma("unroll")                                                               \
        for (int kh = 0; kh < 2; kh++) {                                                \
            bf16x8 af[4], bfv[4];                                                       \
            _Pragma("unroll")                                                           \
            for (int im = 0; im < 4; im++)                                              \
                af[im] = *(const bf16x8*)&As[wm + im * 16 + l16][kh * 32 + quad * 8];   \
            _Pragma("unroll")                                                           \
            for (int in = 0; in < 4; in++)                                              \
                bfv[in] = *(const bf16x8*)&Bs[wn + in * 16 + l16][kh * 32 + quad * 8];  \
            _Pragma("unroll")                                                           \
            for (int im = 0; im < 4; im++)                                              \
                _Pragma("unroll")                                                       \
                for (int in = 0; in < 4; in++)                                          \
                    acc[im][in] = MFMA16(af[im], bfv[in], acc[im][in]);                 \
        }                                                                               \
        __syncthreads();                                                                \
    }

// ---------------- K2: QKV GEMM, 128x128 tiles, bf16 weights ----------------
__global__ __launch_bounds__(256) void qkv_gemm(const __bf16* __restrict__ wbf,
                                                const float* __restrict__ bias,
                                                const __bf16* __restrict__ xnT,
                                                __bf16* __restrict__ qtr,
                                                __bf16* __restrict__ ktr,
                                                __bf16* __restrict__ vbuf) {
    __shared__ __bf16 As[128][72];
    __shared__ __bf16 Bs[128][72];
    const int b = blockIdx.z;
    const int n0 = blockIdx.x * 128, m0 = blockIdx.y * 128;
    const int t = threadIdx.x;
    const int wave = t >> 6, lane = t & 63, quad = lane >> 4, l16 = lane & 15;
    const int wm = (wave & 1) * 64, wn = (wave >> 1) * 64;
    const __bf16* arow = wbf + (size_t)m0 * 256;
    const __bf16* brow = xnT + ((size_t)b * 1024 + n0) * 256;

    GEMM64_BODY(arow, brow)

    #pragma unroll
    for (int im = 0; im < 4; im++) {
        #pragma unroll
        for (int in = 0; in < 4; in++) {
            int sg = n0 + wn + in * 16 + l16;
            int ob = m0 + wm + im * 16 + quad * 4;
            if (m0 < 512) {
                bf16x4 ov;
                #pragma unroll
                for (int r = 0; r < 4; r++) ov[r] = (__bf16)(acc[im][in][r] + bias[ob + r]);
                __bf16* dst = (m0 < 256) ? &qtr[((size_t)b * 1024 + sg) * 256 + ob]
                                         : &ktr[((size_t)b * 1024 + sg) * 256 + (ob - 256)];
                *(bf16x4*)dst = ov;
            } else {
                #pragma unroll
                for (int r = 0; r < 4; r++) {
                    float val = acc[im][in][r] + bias[ob + r];
                    vbuf[((size_t)b * 256 + (ob - 512 + r)) * 1024 + sg] = (__bf16)val;
                }
            }
        }
    }
}

// ---------------- K3: fused flash attention (unchanged from R8) ----------------
__global__ __launch_bounds__(512, 2) void attn_kernel(const __bf16* __restrict__ qtr,
                                                      const __bf16* __restrict__ ktr,
                                                      const __bf16* __restrict__ vbuf,
                                                      __bf16* __restrict__ aoT) {
    __shared__ __bf16 Kt[2][32][260];   // [t-half][t_local][c]
    __shared__ __bf16 Vs[2][256][36];   // [t-half][c][t_local]
    __shared__ __bf16 Pl[4][32][72];    // [pair][s_local][t64]
    __shared__ float Lred[4][2][32];    // [pair][th][row]
    const int b = blockIdx.x;
    const int tid = threadIdx.x;
    const int wave = tid >> 6, lane = tid & 63, half = lane >> 5, l31 = lane & 31;
    const int pair = wave & 3, th = wave >> 2;
    const int s0 = blockIdx.y * 128 + pair * 32;
    const float kscale = 0.09016844f;   // (1/16) * log2(e); p = exp2(s * kscale)

    bf16x8 aq[16];
    #pragma unroll
    for (int ks = 0; ks < 16; ks++)
        aq[ks] = *(const bf16x8*)&qtr[((size_t)b * 1024 + s0 + l31) * 256 + ks * 16 + half * 8];

    const int k_row = tid >> 3;
    const int k_cb  = (tid & 7) * 8;
    const int v_c   = tid >> 1;
    const int v_th  = tid & 1;
    const size_t kbase = (size_t)b * 1024 * 256;
    const size_t vbase = (size_t)b * 256 * 1024;

    float l_part[16] = {};
    f32x16 o_acc[4] = {};

    for (int it = 0; it < 16; it++) {
        const int t0 = it * 64;
        #pragma unroll
        for (int u = 0; u < 4; u++) {
            bf16x8 kv = *(const bf16x8*)&ktr[kbase + (size_t)(t0 + k_row) * 256 + k_cb + u * 64];
            *(bf16x8*)&Kt[k_row >> 5][k_row & 31][k_cb + u * 64] = kv;
        }
        #pragma unroll
        for (int u = 0; u < 4; u++) {
            bf16x8 vv = *(const bf16x8*)&vbuf[vbase + (size_t)v_c * 1024 + t0 + v_th * 32 + u * 8];
            *(bf16x8*)&Vs[v_th][v_c][u * 8] = vv;
        }
        __syncthreads();

        f32x16 sc_a = {}, sc_b = {};
        #pragma unroll
        for (int ks = 0; ks < 8; ks++) {
            bf16x8 bk0 = *(const bf16x8*)&Kt[th][l31][ks * 16 + half * 8];
            bf16x8 bk1 = *(const bf16x8*)&Kt[th][l31][(ks + 8) * 16 + half * 8];
            sc_a = MFMA32(aq[ks], bk0, sc_a);
            sc_b = MFMA32(aq[ks + 8], bk1, sc_b);
        }
        #pragma unroll
        for (int r = 0; r < 16; r++) {
            float p = exp2f((sc_a[r] + sc_b[r]) * kscale);
            l_part[r] += p;
            int row = (r & 3) + 8 * (r >> 2) + 4 * half;
            Pl[pair][row][th * 32 + l31] = (__bf16)p;
        }
        __syncthreads();

        bf16x8 ap[4];
        #pragma unroll
        for (int kc = 0; kc < 4; kc++)
            ap[kc] = *(const bf16x8*)&Pl[pair][l31][kc * 16 + half * 8];
        #pragma unroll
        for (int n = 0; n < 4; n++) {
            int c = th * 128 + n * 32 + l31;
            #pragma unroll
            for (int kc = 0; kc < 4; kc++) {
                bf16x8 bv = *(const bf16x8*)&Vs[kc >> 1][c][(kc & 1) * 16 + half * 8];
                o_acc[n] = MFMA32(ap[kc], bv, o_acc[n]);
            }
        }
        __syncthreads();
    }

    float lsum[16];
    #pragma unroll
    for (int r = 0; r < 16; r++) {
        float l = l_part[r];
        #pragma unroll
        for (int m = 16; m > 0; m >>= 1) l += __shfl_xor(l, m, 32);
        lsum[r] = l;
        if (l31 == 0) {
            int row = (r & 3) + 8 * (r >> 2) + 4 * half;
            Lred[pair][th][row] = l;
        }
    }
    __syncthreads();
    #pragma unroll
    for (int r = 0; r < 16; r++) {
        int row = (r & 3) + 8 * (r >> 2) + 4 * half;
        float rinv = 1.0f / (lsum[r] + Lred[pair][1 - th][row]);
        #pragma unroll
        for (int n = 0; n < 4; n++) {
            int c = th * 128 + n * 32 + l31;
            aoT[((size_t)b * 1024 + s0 + row) * 256 + c] = (__bf16)(o_acc[n][r] * rinv);
        }
    }
}

// ---------------- K4: proj GEMM, 128x128 tiles, bf16 weights ----------------
__global__ __launch_bounds__(256) void proj_gemm(const __bf16* __restrict__ wbf_out,
                                                 const float* __restrict__ bias,
                                                 const __bf16* __restrict__ aoT,
                                                 const float* __restrict__ resid,
                                                 float* __restrict__ Out) {
    __shared__ __bf16 As[128][72];
    __shared__ __bf16 Bs[128][72];
    const int b = blockIdx.z;
    const int n0 = blockIdx.x * 128, m0 = blockIdx.y * 128;
    const int t = threadIdx.x;
    const int wave = t >> 6, lane = t & 63, quad = lane >> 4, l16 = lane & 15;
    const int wm = (wave & 1) * 64, wn = (wave >> 1) * 64;
    const __bf16* arow = wbf_out + (size_t)m0 * 256;
    const __bf16* brow = aoT + ((size_t)b * 1024 + n0) * 256;

    GEMM64_BODY(arow, brow)

    #pragma unroll
    for (int im = 0; im < 4; im++) {
        #pragma unroll
        for (int in = 0; in < 4; in++) {
            int sg = n0 + wn + in * 16 + l16;
            int ob = m0 + wm + im * 16 + quad * 4;
            #pragma unroll
            for (int r = 0; r < 4; r++) {
                int o = ob + r;
                size_t idx = ((size_t)b * 256 + o) * 1024 + sg;
                Out[idx] = acc[im][in][r] + bias[o] + resid[idx];
            }
        }
    }
}

extern "C" void kernel_launch(void* const* d_in, const int* in_sizes, int n_in,
                              void* d_out, int out_size, void* d_ws, size_t ws_size,
                              hipStream_t stream) {
    const float* x    = (const float*)d_in[0];
    const float* gw   = (const float*)d_in[1];
    const float* gb   = (const float*)d_in[2];
    const float* wqkv = (const float*)d_in[3];
    const float* bqkv = (const float*)d_in[4];
    const float* wout = (const float*)d_in[5];
    const float* bout = (const float*)d_in[6];
    float* out = (float*)d_out;

    const size_t T16 = (size_t)32 * 1024 * 256;
    __bf16* xnT  = (__bf16*)d_ws;        // [b][s][c]
    __bf16* qtr  = xnT + T16;            // [b][s][c]
    __bf16* ktr  = qtr + T16;            // [b][t][c]
    __bf16* vbuf = ktr + T16;            // [b][c][t]
    __bf16* aoT  = vbuf + T16;           // [b][s][c]
    __bf16* wbf  = aoT + T16;            // wqkv_bf16 (196608) | wout_bf16 (65536)

    wconv_kernel<<<dim3(128), 256, 0, stream>>>(wqkv, wout, wbf);
    gn_kernel<<<dim3(256), 512, 0, stream>>>(x, gw, gb, xnT);
    qkv_gemm<<<dim3(8, 6, 32), 256, 0, stream>>>(wbf, bqkv, xnT, qtr, ktr, vbuf);
    attn_kernel<<<dim3(32, 8), 512, 0, stream>>>(qtr, ktr, vbuf, aoT);
    proj_gemm<<<dim3(8, 2, 32), 256, 0, stream>>>(wbf + 196608, bout, aoT, x, out);
}